// Round 7
// baseline (197.228 us; speedup 1.0000x reference)
//
#include <hip/hip_runtime.h>

#define NROWS 2048
#define MCOLS 2048

// ---- d_ws layout (float offsets) ----
#define OFF_AF 0                        // 2048 x 20 (padded A rows, fluid)
#define OFF_AS (OFF_AF + NROWS * 20)    // 2048 x 20 (solid)
#define OFF_BF (OFF_AS + NROWS * 20)    // 2048 x 18
#define OFF_BS (OFF_BF + NROWS * 18)    // 2048 x 18
#define OFF_WP (OFF_BS + NROWS * 18)    // 504 packed tail weights
#define OFF_CF (OFF_WP + 512)           // int counts, fluid, 2048
#define OFF_CS (OFF_CF + NROWS)         // int counts, solid, 2048
#define OFF_LISTS (OFF_CS + NROWS)      // u16 lists region
#define LF_CAP ((size_t)NROWS * MCOLS)  // capacity of fluid list region in u16

// packed tail-weight layout (within OFF_WP), fluid then solid (+252)
#define WP_W1 0
#define WP_B1 162
#define WP_W2 171
#define WP_B2 225
#define WP_W3 231
#define WP_B3 249
#define WP_SOLID 252

// exp2-based tanh: absmax 0.5 verified R1-R6. (Pade 3/3 FAILED in R5:
// per-activation systematic error × ~1400-term masked sum -> 48 abs.)
__device__ __forceinline__ float fast_tanh(float x) {
    float t = __builtin_amdgcn_exp2f(x * 2.8853900817779268f);
    return 1.0f - 2.0f * __builtin_amdgcn_rcpf(1.0f + t);
}

// 18->9->6->3 tail on register-resident inputs.
__device__ __forceinline__ void eval_regs(float4 P0, float4 P1, float4 P2,
                                          float4 P3, float2 P4,
                                          const float* __restrict__ Bq,
                                          const float* __restrict__ W,
                                          float& p0, float& p1, float& p2) {
    float h[18];
    h[0]  = fast_tanh(P0.x + Bq[0]);
    h[1]  = fast_tanh(P0.y + Bq[1]);
    h[2]  = fast_tanh(P0.z + Bq[2]);
    h[3]  = fast_tanh(P0.w + Bq[3]);
    h[4]  = fast_tanh(P1.x + Bq[4]);
    h[5]  = fast_tanh(P1.y + Bq[5]);
    h[6]  = fast_tanh(P1.z + Bq[6]);
    h[7]  = fast_tanh(P1.w + Bq[7]);
    h[8]  = fast_tanh(P2.x + Bq[8]);
    h[9]  = fast_tanh(P2.y + Bq[9]);
    h[10] = fast_tanh(P2.z + Bq[10]);
    h[11] = fast_tanh(P2.w + Bq[11]);
    h[12] = fast_tanh(P3.x + Bq[12]);
    h[13] = fast_tanh(P3.y + Bq[13]);
    h[14] = fast_tanh(P3.z + Bq[14]);
    h[15] = fast_tanh(P3.w + Bq[15]);
    h[16] = fast_tanh(P4.x + Bq[16]);
    h[17] = fast_tanh(P4.y + Bq[17]);
    float g[9];
#pragma unroll
    for (int o = 0; o < 9; ++o) g[o] = W[WP_B1 + o];
#pragma unroll
    for (int j = 0; j < 18; ++j) {
        const float a = h[j];
#pragma unroll
        for (int o = 0; o < 9; ++o) g[o] += a * W[WP_W1 + j * 9 + o];
    }
#pragma unroll
    for (int o = 0; o < 9; ++o) g[o] = fast_tanh(g[o]);
    float q[6];
#pragma unroll
    for (int o = 0; o < 6; ++o) q[o] = W[WP_B2 + o];
#pragma unroll
    for (int j = 0; j < 9; ++j) {
        const float a = g[j];
#pragma unroll
        for (int o = 0; o < 6; ++o) q[o] += a * W[WP_W2 + j * 6 + o];
    }
#pragma unroll
    for (int o = 0; o < 6; ++o) q[o] = fast_tanh(q[o]);
    float o0 = W[WP_B3 + 0], o1 = W[WP_B3 + 1], o2 = W[WP_B3 + 2];
#pragma unroll
    for (int j = 0; j < 6; ++j) {
        const float a = q[j];
        o0 += a * W[WP_W3 + j * 3 + 0];
        o1 += a * W[WP_W3 + j * 3 + 1];
        o2 += a * W[WP_W3 + j * 3 + 2];
    }
    p0 += o0; p1 += o1; p2 += o2;
}

// simple: loads inside the loop (32-VGPR body per R6 counters).
__device__ __forceinline__ void row_loop_simple(const float* __restrict__ A,
                                                const unsigned short* __restrict__ lst,
                                                int cnt,
                                                const float* __restrict__ Bq,
                                                const float* __restrict__ W,
                                                int tid,
                                                float& p0, float& p1, float& p2) {
#pragma unroll 1
    for (int i = tid; i < cnt; i += 256) {
        const float* r = A + (int)lst[i] * 20;
        const float4 P0 = *(const float4*)(r);
        const float4 P1 = *(const float4*)(r + 4);
        const float4 P2 = *(const float4*)(r + 8);
        const float4 P3 = *(const float4*)(r + 12);
        const float2 P4 = *(const float2*)(r + 16);
        eval_regs(P0, P1, P2, P3, P4, Bq, W, p0, p1, p2);
    }
}

// pipe: 2-deep software pipeline — prefetch next A-row into regs while
// computing current, rotate.
__device__ __forceinline__ void row_loop_pipe(const float* __restrict__ A,
                                              const unsigned short* __restrict__ lst,
                                              int cnt,
                                              const float* __restrict__ Bq,
                                              const float* __restrict__ W,
                                              int tid,
                                              float& p0, float& p1, float& p2) {
    int i = tid;
    if (i >= cnt) return;
    const float* r = A + (int)lst[i] * 20;
    float4 P0 = *(const float4*)(r);
    float4 P1 = *(const float4*)(r + 4);
    float4 P2 = *(const float4*)(r + 8);
    float4 P3 = *(const float4*)(r + 12);
    float2 P4 = *(const float2*)(r + 16);
    for (;;) {
        const int inext = i + 256;
        const bool more = inext < cnt;
        const float* rn = A + (int)lst[more ? inext : i] * 20;
        const float4 N0 = *(const float4*)(rn);
        const float4 N1 = *(const float4*)(rn + 4);
        const float4 N2 = *(const float4*)(rn + 8);
        const float4 N3 = *(const float4*)(rn + 12);
        const float2 N4 = *(const float2*)(rn + 16);
        eval_regs(P0, P1, P2, P3, P4, Bq, W, p0, p1, p2);
        if (!more) break;
        P0 = N0; P1 = N1; P2 = N2; P3 = N3; P4 = N4;
        i = inext;
    }
}

__global__ void prep_kernel(const int* __restrict__ index,
                            const float* __restrict__ data,
                            const float* __restrict__ wf0, const float* __restrict__ bf0,
                            const float* __restrict__ sw0, const float* __restrict__ sb0,
                            const float* __restrict__ wf1, const float* __restrict__ bf1,
                            const float* __restrict__ wf2, const float* __restrict__ bf2,
                            const float* __restrict__ wf3, const float* __restrict__ bf3,
                            const float* __restrict__ sw1, const float* __restrict__ sb1,
                            const float* __restrict__ sw2, const float* __restrict__ sb2,
                            const float* __restrict__ sw3, const float* __restrict__ sb3,
                            float* __restrict__ wsp) {
    int i = blockIdx.x * blockDim.x + threadIdx.x;
    if (i < NROWS) {
        float d[7], cen[7];
#pragma unroll
        for (int c = 0; c < 7; ++c) d[c] = data[i * 7 + c];
        int ci = index[i];
#pragma unroll
        for (int c = 0; c < 7; ++c) cen[c] = data[ci * 7 + c];
#pragma unroll
        for (int j = 0; j < 18; ++j) {
            float af = 0.f;
#pragma unroll
            for (int c = 0; c < 7; ++c) af += d[c] * wf0[c * 18 + j];
            float as = d[0] * sw0[0 * 18 + j] + d[1] * sw0[1 * 18 + j] + d[2] * sw0[2 * 18 + j];
            float bf = bf0[j], bs = sb0[j];
#pragma unroll
            for (int c = 0; c < 3; ++c) bf -= cen[c] * wf0[c * 18 + j];
#pragma unroll
            for (int c = 0; c < 4; ++c) bf += cen[3 + c] * wf0[(7 + c) * 18 + j];
#pragma unroll
            for (int c = 0; c < 3; ++c) bs -= cen[c] * sw0[c * 18 + j];
#pragma unroll
            for (int c = 0; c < 4; ++c) bs += cen[3 + c] * sw0[(3 + c) * 18 + j];
            wsp[OFF_AF + i * 20 + j] = af;
            wsp[OFF_AS + i * 20 + j] = as;
            wsp[OFF_BF + i * 18 + j] = bf;
            wsp[OFF_BS + i * 18 + j] = bs;
        }
        wsp[OFF_AF + i * 20 + 18] = 0.f; wsp[OFF_AF + i * 20 + 19] = 0.f;
        wsp[OFF_AS + i * 20 + 18] = 0.f; wsp[OFF_AS + i * 20 + 19] = 0.f;
    }
    if (blockIdx.x == 0) {
        int t = threadIdx.x;
        float* wp = wsp + OFF_WP;
        for (int k = t; k < 162; k += 256) wp[WP_W1 + k] = wf1[k];
        for (int k = t; k < 9;   k += 256) wp[WP_B1 + k] = bf1[k];
        for (int k = t; k < 54;  k += 256) wp[WP_W2 + k] = wf2[k];
        for (int k = t; k < 6;   k += 256) wp[WP_B2 + k] = bf2[k];
        for (int k = t; k < 18;  k += 256) wp[WP_W3 + k] = wf3[k];
        for (int k = t; k < 3;   k += 256) wp[WP_B3 + k] = bf3[k];
        for (int k = t; k < 162; k += 256) wp[WP_SOLID + WP_W1 + k] = sw1[k];
        for (int k = t; k < 9;   k += 256) wp[WP_SOLID + WP_B1 + k] = sb1[k];
        for (int k = t; k < 54;  k += 256) wp[WP_SOLID + WP_W2 + k] = sw2[k];
        for (int k = t; k < 6;   k += 256) wp[WP_SOLID + WP_B2 + k] = sb2[k];
        for (int k = t; k < 18;  k += 256) wp[WP_SOLID + WP_W3 + k] = sw3[k];
        for (int k = t; k < 3;   k += 256) wp[WP_SOLID + WP_B3 + k] = sb3[k];
    }
}

__global__ __launch_bounds__(256)
void compact_kernel(const int* __restrict__ mask,
                    const float* __restrict__ data,
                    float* __restrict__ wsp) {
    const int lane = threadIdx.x & 63;
    const int n = blockIdx.x * 4 + (threadIdx.x >> 6);
    int* counts_f = (int*)(wsp + OFF_CF);
    int* counts_s = (int*)(wsp + OFF_CS);
    unsigned short* lf = (unsigned short*)(wsp + OFF_LISTS) + (size_t)n * MCOLS;
    unsigned short* ls = lf + LF_CAP;
    const int* mrow = mask + (size_t)n * MCOLS;
    int bf = 0, bs = 0;
    const unsigned long long ltmask = (1ull << lane) - 1ull;
#pragma unroll 1
    for (int it = 0; it < MCOLS / 64; ++it) {
        const int m = it * 64 + lane;
        const int mk = mrow[m];
        const float flag = data[m * 7 + 6];
        const bool af = mk && (flag > 0.f);
        const bool as = mk && (flag < 1.f);
        const unsigned long long balf = __ballot(af);
        const unsigned long long bals = __ballot(as);
        if (af) lf[bf + __popcll(balf & ltmask)] = (unsigned short)m;
        if (as) ls[bs + __popcll(bals & ltmask)] = (unsigned short)m;
        bf += __popcll(balf);
        bs += __popcll(bals);
    }
    if (lane == 0) { counts_f[n] = bf; counts_s[n] = bs; }
}

template <int VAR>
__device__ __forceinline__ void main_body(const float* __restrict__ wsp,
                                          float* __restrict__ out) {
    const int n = blockIdx.x;
    const int tid = threadIdx.x;
    __shared__ float red[3][4];
    const float* __restrict__ W  = wsp + OFF_WP;
    const float* __restrict__ Bf = wsp + OFF_BF + n * 18;
    const float* __restrict__ Bs = wsp + OFF_BS + n * 18;
    const int cf = ((const int*)(wsp + OFF_CF))[n];
    const int cs = ((const int*)(wsp + OFF_CS))[n];
    const unsigned short* lf = (const unsigned short*)(wsp + OFF_LISTS) + (size_t)n * MCOLS;
    const unsigned short* ls = lf + LF_CAP;

    float p0 = 0.f, p1 = 0.f, p2 = 0.f;
    if (VAR == 0) {
        row_loop_simple(wsp + OFF_AF, lf, cf, Bf, W, tid, p0, p1, p2);
        row_loop_simple(wsp + OFF_AS, ls, cs, Bs, W + WP_SOLID, tid, p0, p1, p2);
    } else {
        row_loop_pipe(wsp + OFF_AF, lf, cf, Bf, W, tid, p0, p1, p2);
        row_loop_pipe(wsp + OFF_AS, ls, cs, Bs, W + WP_SOLID, tid, p0, p1, p2);
    }

#pragma unroll
    for (int off = 32; off > 0; off >>= 1) {
        p0 += __shfl_xor(p0, off, 64);
        p1 += __shfl_xor(p1, off, 64);
        p2 += __shfl_xor(p2, off, 64);
    }
    const int wid = tid >> 6;
    if ((tid & 63) == 0) { red[0][wid] = p0; red[1][wid] = p1; red[2][wid] = p2; }
    __syncthreads();
    if (tid == 0) {
        float s0 = 0.f, s1 = 0.f, s2 = 0.f;
#pragma unroll
        for (int w = 0; w < 4; ++w) { s0 += red[0][w]; s1 += red[1][w]; s2 += red[2][w]; }
        out[n * 3 + 0] = s0; out[n * 3 + 1] = s1; out[n * 3 + 2] = s2;
    }
}

// R7 A/B: occupancy experiment.
// A = simple body, 8 waves/EU requested (body fit 32 VGPR in R6 -> no spill expected).
// B = pipeline @ (256,4), the R6 winner (~82 us), runs LAST (validated result).
__global__ __launch_bounds__(256, 8)
void main_hi(const float* __restrict__ wsp, float* __restrict__ out) {
    main_body<0>(wsp, out);
}

__global__ __launch_bounds__(256, 4)
void main_pipe(const float* __restrict__ wsp, float* __restrict__ out) {
    main_body<1>(wsp, out);
}

extern "C" void kernel_launch(void* const* d_in, const int* in_sizes, int n_in,
                              void* d_out, int out_size, void* d_ws, size_t ws_size,
                              hipStream_t stream) {
    const int*   mask  = (const int*)d_in[0];
    const int*   index = (const int*)d_in[1];
    const float* data  = (const float*)d_in[2];
    const float* wf0   = (const float*)d_in[3];
    const float* bf0   = (const float*)d_in[4];
    const float* wf1   = (const float*)d_in[5];
    const float* bf1   = (const float*)d_in[6];
    const float* wf2   = (const float*)d_in[7];
    const float* bf2   = (const float*)d_in[8];
    const float* wf3   = (const float*)d_in[9];
    const float* bf3   = (const float*)d_in[10];
    const float* sw0   = (const float*)d_in[11];
    const float* sb0   = (const float*)d_in[12];
    const float* sw1   = (const float*)d_in[13];
    const float* sb1   = (const float*)d_in[14];
    const float* sw2   = (const float*)d_in[15];
    const float* sb2   = (const float*)d_in[16];
    const float* sw3   = (const float*)d_in[17];
    const float* sb3   = (const float*)d_in[18];
    float* wsp = (float*)d_ws;
    float* out = (float*)d_out;

    prep_kernel<<<dim3(8), dim3(256), 0, stream>>>(
        index, data, wf0, bf0, sw0, sb0, wf1, bf1, wf2, bf2, wf3, bf3,
        sw1, sb1, sw2, sb2, sw3, sb3, wsp);
    compact_kernel<<<dim3(NROWS / 4), dim3(256), 0, stream>>>(mask, data, wsp);
    main_hi<<<dim3(NROWS), dim3(256), 0, stream>>>(wsp, out);
    main_pipe<<<dim3(NROWS), dim3(256), 0, stream>>>(wsp, out);
}

// Round 8
// 174.848 us; speedup vs baseline: 1.1280x; 1.1280x over previous
//
#include <hip/hip_runtime.h>

#define NROWS 2048
#define MCOLS 2048

// ---- d_ws layout (float offsets) ----
#define OFF_AF 0                        // 2048 x 20 (padded A rows, fluid)
#define OFF_AS (OFF_AF + NROWS * 20)    // 2048 x 20 (solid)
#define OFF_BF (OFF_AS + NROWS * 20)    // 2048 x 18
#define OFF_BS (OFF_BF + NROWS * 18)    // 2048 x 18
#define OFF_WP (OFF_BS + NROWS * 18)    // 504 packed tail weights
#define OFF_CF (OFF_WP + 512)           // int counts, fluid, 2048
#define OFF_CS (OFF_CF + NROWS)         // int counts, solid, 2048
#define OFF_LISTS (OFF_CS + NROWS)      // u16 lists region
#define LF_CAP ((size_t)NROWS * MCOLS)  // capacity of fluid list region in u16

// packed tail-weight layout (within OFF_WP), fluid then solid (+252)
#define WP_W1 0
#define WP_B1 162
#define WP_W2 171
#define WP_B2 225
#define WP_W3 231
#define WP_B3 249
#define WP_SOLID 252

typedef float v2f __attribute__((ext_vector_type(2)));

__device__ __forceinline__ v2f SP(float s) { return (v2f){s, s}; }

// exp2-based tanh: absmax 0.5 verified R1-R7. (Pade 3/3 FAILED in R5.)
__device__ __forceinline__ float fast_tanh(float x) {
    float t = __builtin_amdgcn_exp2f(x * 2.8853900817779268f);
    return 1.0f - 2.0f * __builtin_amdgcn_rcpf(1.0f + t);
}

// packed-pair tanh: pk ops around scalar exp2/rcp; same fp32 math per lane-eval.
__device__ __forceinline__ v2f vtanh(v2f x) {
    v2f xs = x * SP(2.8853900817779268f);          // v_pk_mul
    v2f t;
    t.x = __builtin_amdgcn_exp2f(xs.x);
    t.y = __builtin_amdgcn_exp2f(xs.y);
    v2f d = t + SP(1.0f);                          // v_pk_add
    v2f r;
    r.x = __builtin_amdgcn_rcpf(d.x);
    r.y = __builtin_amdgcn_rcpf(d.y);
    return SP(1.0f) - SP(2.0f) * r;                // v_pk_fma
}

// 18->9->6->3 tail on register-resident inputs (scalar, for tails/control).
__device__ __forceinline__ void eval_regs(float4 P0, float4 P1, float4 P2,
                                          float4 P3, float2 P4,
                                          const float* __restrict__ Bq,
                                          const float* __restrict__ W,
                                          float& p0, float& p1, float& p2) {
    float h[18];
    h[0]  = fast_tanh(P0.x + Bq[0]);
    h[1]  = fast_tanh(P0.y + Bq[1]);
    h[2]  = fast_tanh(P0.z + Bq[2]);
    h[3]  = fast_tanh(P0.w + Bq[3]);
    h[4]  = fast_tanh(P1.x + Bq[4]);
    h[5]  = fast_tanh(P1.y + Bq[5]);
    h[6]  = fast_tanh(P1.z + Bq[6]);
    h[7]  = fast_tanh(P1.w + Bq[7]);
    h[8]  = fast_tanh(P2.x + Bq[8]);
    h[9]  = fast_tanh(P2.y + Bq[9]);
    h[10] = fast_tanh(P2.z + Bq[10]);
    h[11] = fast_tanh(P2.w + Bq[11]);
    h[12] = fast_tanh(P3.x + Bq[12]);
    h[13] = fast_tanh(P3.y + Bq[13]);
    h[14] = fast_tanh(P3.z + Bq[14]);
    h[15] = fast_tanh(P3.w + Bq[15]);
    h[16] = fast_tanh(P4.x + Bq[16]);
    h[17] = fast_tanh(P4.y + Bq[17]);
    float g[9];
#pragma unroll
    for (int o = 0; o < 9; ++o) g[o] = W[WP_B1 + o];
#pragma unroll
    for (int j = 0; j < 18; ++j) {
        const float a = h[j];
#pragma unroll
        for (int o = 0; o < 9; ++o) g[o] += a * W[WP_W1 + j * 9 + o];
    }
#pragma unroll
    for (int o = 0; o < 9; ++o) g[o] = fast_tanh(g[o]);
    float q[6];
#pragma unroll
    for (int o = 0; o < 6; ++o) q[o] = W[WP_B2 + o];
#pragma unroll
    for (int j = 0; j < 9; ++j) {
        const float a = g[j];
#pragma unroll
        for (int o = 0; o < 6; ++o) q[o] += a * W[WP_W2 + j * 6 + o];
    }
#pragma unroll
    for (int o = 0; o < 6; ++o) q[o] = fast_tanh(q[o]);
    float o0 = W[WP_B3 + 0], o1 = W[WP_B3 + 1], o2 = W[WP_B3 + 2];
#pragma unroll
    for (int j = 0; j < 6; ++j) {
        const float a = q[j];
        o0 += a * W[WP_W3 + j * 3 + 0];
        o1 += a * W[WP_W3 + j * 3 + 1];
        o2 += a * W[WP_W3 + j * 3 + 2];
    }
    p0 += o0; p1 += o1; p2 += o2;
}

__device__ __forceinline__ void eval_single(const float* __restrict__ A, int m,
                                            const float* __restrict__ Bq,
                                            const float* __restrict__ W,
                                            float& p0, float& p1, float& p2) {
    const float* r = A + m * 20;
    eval_regs(*(const float4*)(r), *(const float4*)(r + 4),
              *(const float4*)(r + 8), *(const float4*)(r + 12),
              *(const float2*)(r + 16), Bq, W, p0, p1, p2);
}

// V1: TWO evals per thread, state as v2f -> v_pk_fma_f32 for all layer math.
__device__ __forceinline__ void eval_pair(const float* __restrict__ A,
                                          int m0, int m1,
                                          const float* __restrict__ Bq,
                                          const float* __restrict__ W,
                                          v2f& s0, v2f& s1, v2f& s2) {
    const float* r0 = A + m0 * 20;
    const float* r1 = A + m1 * 20;
    const float4 X0 = *(const float4*)(r0);
    const float4 X1 = *(const float4*)(r0 + 4);
    const float4 X2 = *(const float4*)(r0 + 8);
    const float4 X3 = *(const float4*)(r0 + 12);
    const float2 X4 = *(const float2*)(r0 + 16);
    const float4 Y0 = *(const float4*)(r1);
    const float4 Y1 = *(const float4*)(r1 + 4);
    const float4 Y2 = *(const float4*)(r1 + 8);
    const float4 Y3 = *(const float4*)(r1 + 12);
    const float2 Y4 = *(const float2*)(r1 + 16);
    v2f h[18];
    h[0]  = vtanh((v2f){X0.x, Y0.x} + SP(Bq[0]));
    h[1]  = vtanh((v2f){X0.y, Y0.y} + SP(Bq[1]));
    h[2]  = vtanh((v2f){X0.z, Y0.z} + SP(Bq[2]));
    h[3]  = vtanh((v2f){X0.w, Y0.w} + SP(Bq[3]));
    h[4]  = vtanh((v2f){X1.x, Y1.x} + SP(Bq[4]));
    h[5]  = vtanh((v2f){X1.y, Y1.y} + SP(Bq[5]));
    h[6]  = vtanh((v2f){X1.z, Y1.z} + SP(Bq[6]));
    h[7]  = vtanh((v2f){X1.w, Y1.w} + SP(Bq[7]));
    h[8]  = vtanh((v2f){X2.x, Y2.x} + SP(Bq[8]));
    h[9]  = vtanh((v2f){X2.y, Y2.y} + SP(Bq[9]));
    h[10] = vtanh((v2f){X2.z, Y2.z} + SP(Bq[10]));
    h[11] = vtanh((v2f){X2.w, Y2.w} + SP(Bq[11]));
    h[12] = vtanh((v2f){X3.x, Y3.x} + SP(Bq[12]));
    h[13] = vtanh((v2f){X3.y, Y3.y} + SP(Bq[13]));
    h[14] = vtanh((v2f){X3.z, Y3.z} + SP(Bq[14]));
    h[15] = vtanh((v2f){X3.w, Y3.w} + SP(Bq[15]));
    h[16] = vtanh((v2f){X4.x, Y4.x} + SP(Bq[16]));
    h[17] = vtanh((v2f){X4.y, Y4.y} + SP(Bq[17]));
    v2f g[9];
#pragma unroll
    for (int o = 0; o < 9; ++o) g[o] = SP(W[WP_B1 + o]);
#pragma unroll
    for (int j = 0; j < 18; ++j) {
        const v2f a = h[j];
#pragma unroll
        for (int o = 0; o < 9; ++o) g[o] += a * SP(W[WP_W1 + j * 9 + o]);
    }
#pragma unroll
    for (int o = 0; o < 9; ++o) g[o] = vtanh(g[o]);
    v2f q[6];
#pragma unroll
    for (int o = 0; o < 6; ++o) q[o] = SP(W[WP_B2 + o]);
#pragma unroll
    for (int j = 0; j < 9; ++j) {
        const v2f a = g[j];
#pragma unroll
        for (int o = 0; o < 6; ++o) q[o] += a * SP(W[WP_W2 + j * 6 + o]);
    }
#pragma unroll
    for (int o = 0; o < 6; ++o) q[o] = vtanh(q[o]);
    v2f o0 = SP(W[WP_B3 + 0]), o1 = SP(W[WP_B3 + 1]), o2 = SP(W[WP_B3 + 2]);
#pragma unroll
    for (int j = 0; j < 6; ++j) {
        const v2f a = q[j];
        o0 += a * SP(W[WP_W3 + j * 3 + 0]);
        o1 += a * SP(W[WP_W3 + j * 3 + 1]);
        o2 += a * SP(W[WP_W3 + j * 3 + 2]);
    }
    s0 += o0; s1 += o1; s2 += o2;
}

// V0 control: 2-deep software-pipelined scalar loop (R6 winner).
__device__ __forceinline__ void row_loop_pipe(const float* __restrict__ A,
                                              const unsigned short* __restrict__ lst,
                                              int cnt,
                                              const float* __restrict__ Bq,
                                              const float* __restrict__ W,
                                              int tid,
                                              float& p0, float& p1, float& p2) {
    int i = tid;
    if (i >= cnt) return;
    const float* r = A + (int)lst[i] * 20;
    float4 P0 = *(const float4*)(r);
    float4 P1 = *(const float4*)(r + 4);
    float4 P2 = *(const float4*)(r + 8);
    float4 P3 = *(const float4*)(r + 12);
    float2 P4 = *(const float2*)(r + 16);
    for (;;) {
        const int inext = i + 256;
        const bool more = inext < cnt;
        const float* rn = A + (int)lst[more ? inext : i] * 20;
        const float4 N0 = *(const float4*)(rn);
        const float4 N1 = *(const float4*)(rn + 4);
        const float4 N2 = *(const float4*)(rn + 8);
        const float4 N3 = *(const float4*)(rn + 12);
        const float2 N4 = *(const float2*)(rn + 16);
        eval_regs(P0, P1, P2, P3, P4, Bq, W, p0, p1, p2);
        if (!more) break;
        P0 = N0; P1 = N1; P2 = N2; P3 = N3; P4 = N4;
        i = inext;
    }
}

// V1: paired-pk loop, list read as packed u16 pairs.
__device__ __forceinline__ void row_loop_pair(const float* __restrict__ A,
                                              const unsigned short* __restrict__ lst,
                                              int cnt,
                                              const float* __restrict__ Bq,
                                              const float* __restrict__ W,
                                              int tid,
                                              v2f& s0, v2f& s1, v2f& s2,
                                              float& p0, float& p1, float& p2) {
    const unsigned int* l32 = (const unsigned int*)lst;
    const int np = cnt >> 1;
#pragma unroll 1
    for (int i = tid; i < np; i += 256) {
        const unsigned int mm = l32[i];
        eval_pair(A, (int)(mm & 0xffffu), (int)(mm >> 16), Bq, W, s0, s1, s2);
    }
    if ((cnt & 1) && tid == 0)
        eval_single(A, lst[cnt - 1], Bq, W, p0, p1, p2);
}

__global__ void prep_kernel(const int* __restrict__ index,
                            const float* __restrict__ data,
                            const float* __restrict__ wf0, const float* __restrict__ bf0,
                            const float* __restrict__ sw0, const float* __restrict__ sb0,
                            const float* __restrict__ wf1, const float* __restrict__ bf1,
                            const float* __restrict__ wf2, const float* __restrict__ bf2,
                            const float* __restrict__ wf3, const float* __restrict__ bf3,
                            const float* __restrict__ sw1, const float* __restrict__ sb1,
                            const float* __restrict__ sw2, const float* __restrict__ sb2,
                            const float* __restrict__ sw3, const float* __restrict__ sb3,
                            float* __restrict__ wsp) {
    int i = blockIdx.x * blockDim.x + threadIdx.x;
    if (i < NROWS) {
        float d[7], cen[7];
#pragma unroll
        for (int c = 0; c < 7; ++c) d[c] = data[i * 7 + c];
        int ci = index[i];
#pragma unroll
        for (int c = 0; c < 7; ++c) cen[c] = data[ci * 7 + c];
#pragma unroll
        for (int j = 0; j < 18; ++j) {
            float af = 0.f;
#pragma unroll
            for (int c = 0; c < 7; ++c) af += d[c] * wf0[c * 18 + j];
            float as = d[0] * sw0[0 * 18 + j] + d[1] * sw0[1 * 18 + j] + d[2] * sw0[2 * 18 + j];
            float bf = bf0[j], bs = sb0[j];
#pragma unroll
            for (int c = 0; c < 3; ++c) bf -= cen[c] * wf0[c * 18 + j];
#pragma unroll
            for (int c = 0; c < 4; ++c) bf += cen[3 + c] * wf0[(7 + c) * 18 + j];
#pragma unroll
            for (int c = 0; c < 3; ++c) bs -= cen[c] * sw0[c * 18 + j];
#pragma unroll
            for (int c = 0; c < 4; ++c) bs += cen[3 + c] * sw0[(3 + c) * 18 + j];
            wsp[OFF_AF + i * 20 + j] = af;
            wsp[OFF_AS + i * 20 + j] = as;
            wsp[OFF_BF + i * 18 + j] = bf;
            wsp[OFF_BS + i * 18 + j] = bs;
        }
        wsp[OFF_AF + i * 20 + 18] = 0.f; wsp[OFF_AF + i * 20 + 19] = 0.f;
        wsp[OFF_AS + i * 20 + 18] = 0.f; wsp[OFF_AS + i * 20 + 19] = 0.f;
    }
    if (blockIdx.x == 0) {
        int t = threadIdx.x;
        float* wp = wsp + OFF_WP;
        for (int k = t; k < 162; k += 256) wp[WP_W1 + k] = wf1[k];
        for (int k = t; k < 9;   k += 256) wp[WP_B1 + k] = bf1[k];
        for (int k = t; k < 54;  k += 256) wp[WP_W2 + k] = wf2[k];
        for (int k = t; k < 6;   k += 256) wp[WP_B2 + k] = bf2[k];
        for (int k = t; k < 18;  k += 256) wp[WP_W3 + k] = wf3[k];
        for (int k = t; k < 3;   k += 256) wp[WP_B3 + k] = bf3[k];
        for (int k = t; k < 162; k += 256) wp[WP_SOLID + WP_W1 + k] = sw1[k];
        for (int k = t; k < 9;   k += 256) wp[WP_SOLID + WP_B1 + k] = sb1[k];
        for (int k = t; k < 54;  k += 256) wp[WP_SOLID + WP_W2 + k] = sw2[k];
        for (int k = t; k < 6;   k += 256) wp[WP_SOLID + WP_B2 + k] = sb2[k];
        for (int k = t; k < 18;  k += 256) wp[WP_SOLID + WP_W3 + k] = sw3[k];
        for (int k = t; k < 3;   k += 256) wp[WP_SOLID + WP_B3 + k] = sb3[k];
    }
}

__global__ __launch_bounds__(256)
void compact_kernel(const int* __restrict__ mask,
                    const float* __restrict__ data,
                    float* __restrict__ wsp) {
    const int lane = threadIdx.x & 63;
    const int n = blockIdx.x * 4 + (threadIdx.x >> 6);
    int* counts_f = (int*)(wsp + OFF_CF);
    int* counts_s = (int*)(wsp + OFF_CS);
    unsigned short* lf = (unsigned short*)(wsp + OFF_LISTS) + (size_t)n * MCOLS;
    unsigned short* ls = lf + LF_CAP;
    const int* mrow = mask + (size_t)n * MCOLS;
    int bf = 0, bs = 0;
    const unsigned long long ltmask = (1ull << lane) - 1ull;
#pragma unroll 1
    for (int it = 0; it < MCOLS / 64; ++it) {
        const int m = it * 64 + lane;
        const int mk = mrow[m];
        const float flag = data[m * 7 + 6];
        const bool af = mk && (flag > 0.f);
        const bool as = mk && (flag < 1.f);
        const unsigned long long balf = __ballot(af);
        const unsigned long long bals = __ballot(as);
        if (af) lf[bf + __popcll(balf & ltmask)] = (unsigned short)m;
        if (as) ls[bs + __popcll(bals & ltmask)] = (unsigned short)m;
        bf += __popcll(balf);
        bs += __popcll(bals);
    }
    if (lane == 0) { counts_f[n] = bf; counts_s[n] = bs; }
}

template <int VAR>
__device__ __forceinline__ void main_body(const float* __restrict__ wsp,
                                          float* __restrict__ out) {
    const int n = blockIdx.x;
    const int tid = threadIdx.x;
    __shared__ float red[3][4];
    const float* __restrict__ W  = wsp + OFF_WP;
    const float* __restrict__ Bf = wsp + OFF_BF + n * 18;
    const float* __restrict__ Bs = wsp + OFF_BS + n * 18;
    const int cf = ((const int*)(wsp + OFF_CF))[n];
    const int cs = ((const int*)(wsp + OFF_CS))[n];
    const unsigned short* lf = (const unsigned short*)(wsp + OFF_LISTS) + (size_t)n * MCOLS;
    const unsigned short* ls = lf + LF_CAP;

    float p0 = 0.f, p1 = 0.f, p2 = 0.f;
    if (VAR == 0) {
        row_loop_pipe(wsp + OFF_AF, lf, cf, Bf, W, tid, p0, p1, p2);
        row_loop_pipe(wsp + OFF_AS, ls, cs, Bs, W + WP_SOLID, tid, p0, p1, p2);
    } else {
        v2f s0 = SP(0.f), s1 = SP(0.f), s2 = SP(0.f);
        row_loop_pair(wsp + OFF_AF, lf, cf, Bf, W, tid, s0, s1, s2, p0, p1, p2);
        row_loop_pair(wsp + OFF_AS, ls, cs, Bs, W + WP_SOLID, tid, s0, s1, s2, p0, p1, p2);
        p0 += s0.x + s0.y; p1 += s1.x + s1.y; p2 += s2.x + s2.y;
    }

#pragma unroll
    for (int off = 32; off > 0; off >>= 1) {
        p0 += __shfl_xor(p0, off, 64);
        p1 += __shfl_xor(p1, off, 64);
        p2 += __shfl_xor(p2, off, 64);
    }
    const int wid = tid >> 6;
    if ((tid & 63) == 0) { red[0][wid] = p0; red[1][wid] = p1; red[2][wid] = p2; }
    __syncthreads();
    if (tid == 0) {
        float s0 = 0.f, s1 = 0.f, s2 = 0.f;
#pragma unroll
        for (int w = 0; w < 4; ++w) { s0 += red[0][w]; s1 += red[1][w]; s2 += red[2][w]; }
        out[n * 3 + 0] = s0; out[n * 3 + 1] = s1; out[n * 3 + 2] = s2;
    }
}

// R8 A/B: packed-fp32 pair eval vs pipelined scalar control.
// main_pair runs LAST -> its full overwrite of `out` is validated.
__global__ __launch_bounds__(256, 4)
void main_pipe(const float* __restrict__ wsp, float* __restrict__ out) {
    main_body<0>(wsp, out);
}

__global__ __launch_bounds__(256, 4)
void main_pair(const float* __restrict__ wsp, float* __restrict__ out) {
    main_body<1>(wsp, out);
}

extern "C" void kernel_launch(void* const* d_in, const int* in_sizes, int n_in,
                              void* d_out, int out_size, void* d_ws, size_t ws_size,
                              hipStream_t stream) {
    const int*   mask  = (const int*)d_in[0];
    const int*   index = (const int*)d_in[1];
    const float* data  = (const float*)d_in[2];
    const float* wf0   = (const float*)d_in[3];
    const float* bf0   = (const float*)d_in[4];
    const float* wf1   = (const float*)d_in[5];
    const float* bf1   = (const float*)d_in[6];
    const float* wf2   = (const float*)d_in[7];
    const float* bf2   = (const float*)d_in[8];
    const float* wf3   = (const float*)d_in[9];
    const float* bf3   = (const float*)d_in[10];
    const float* sw0   = (const float*)d_in[11];
    const float* sb0   = (const float*)d_in[12];
    const float* sw1   = (const float*)d_in[13];
    const float* sb1   = (const float*)d_in[14];
    const float* sw2   = (const float*)d_in[15];
    const float* sb2   = (const float*)d_in[16];
    const float* sw3   = (const float*)d_in[17];
    const float* sb3   = (const float*)d_in[18];
    float* wsp = (float*)d_ws;
    float* out = (float*)d_out;

    prep_kernel<<<dim3(8), dim3(256), 0, stream>>>(
        index, data, wf0, bf0, sw0, sb0, wf1, bf1, wf2, bf2, wf3, bf3,
        sw1, sb1, sw2, sb2, sw3, sb3, wsp);
    compact_kernel<<<dim3(NROWS / 4), dim3(256), 0, stream>>>(mask, data, wsp);
    main_pipe<<<dim3(NROWS), dim3(256), 0, stream>>>(wsp, out);
    main_pair<<<dim3(NROWS), dim3(256), 0, stream>>>(wsp, out);
}